// Round 3
// baseline (144.755 us; speedup 1.0000x reference)
//
#include <hip/hip_runtime.h>
#include <hip/hip_fp16.h>

// BackProjectionLinear: out[b,p] = sum_d apod[d] * lerp(sino[b,d], k[p,d], a[p,d]) / 63.5
// B=4, N_DET=128, N_T=2048, pixels=65536.
//
// R13: R12's det-major dataflow (coalesced 1KB/wave lut, one 16B L2 gather
// per (px,det) covering both taps x 4 batches, zero LDS) was right, but the
// per-pixel serial DPP reduce inside the loop pinned the schedule: VGPR=32,
// ~1.5 loads in flight/wave, HBM 1.26 TB/s, 56.7us. Restructure into three
// phases so the load loop has NO cross-lane ops and no loop-carried deps:
//   A: issue all 8 lut loads (nt) up front.
//   B: per 4-px subgroup: issue 8 gathers into arrays, then lerp into
//      per-lane acc[8][4]. Loads decoupled from use -> deep MLP.
//   C: 32 butterflies + lane-j commits, after all loads drained.
// Canary: VGPR ~100-120 (pipelining happened), WRITE_SIZE ~1.1MB (no spill).

#define NB      4
#define NDET    128
#define NT      2048
#define NPIX    65536
#define PXW     8                    // pixels per wave

typedef unsigned uv4 __attribute__((ext_vector_type(4)));

// ---- pass 1: sino fp32[4][128][2048] -> ws16b[det][t] = uint4
//      {h2(b01@t), h2(b23@t), h2(b01@t+1), h2(b23@t+1)}  (4 MB) ----
__global__ __launch_bounds__(256)
void cvt16b(const float* __restrict__ sino, uint4* __restrict__ ws) {
    const int id = blockIdx.x * 256 + threadIdx.x;     // det*NT + t
    const int t  = id & (NT - 1);
    float c0 = sino[id];
    float c1 = sino[id +     NDET * NT];
    float c2 = sino[id + 2 * NDET * NT];
    float c3 = sino[id + 3 * NDET * NT];
    const int idn = (t < NT - 1) ? id + 1 : id;        // t=2047 entry never gathered
    float n0 = sino[idn];
    float n1 = sino[idn +     NDET * NT];
    float n2 = sino[idn + 2 * NDET * NT];
    float n3 = sino[idn + 3 * NDET * NT];
    uint4 u;
    __half2 h;
    h = __floats2half2_rn(c0, c1); u.x = *(unsigned*)&h;
    h = __floats2half2_rn(c2, c3); u.y = *(unsigned*)&h;
    h = __floats2half2_rn(n0, n1); u.z = *(unsigned*)&h;
    h = __floats2half2_rn(n2, n3); u.w = *(unsigned*)&h;
    ws[id] = u;
}

// 64-lane f32 add-reduce on the VALU pipe. Result valid in lane 63.
__device__ __forceinline__ float wave_reduce_add(float v) {
    int x;
    x = __builtin_amdgcn_update_dpp(0, __float_as_int(v), 0xB1,  0xF, 0xF, true); v += __int_as_float(x); // quad_perm [1,0,3,2]
    x = __builtin_amdgcn_update_dpp(0, __float_as_int(v), 0x4E,  0xF, 0xF, true); v += __int_as_float(x); // quad_perm [2,3,0,1]
    x = __builtin_amdgcn_update_dpp(0, __float_as_int(v), 0x141, 0xF, 0xF, true); v += __int_as_float(x); // row_half_mirror
    x = __builtin_amdgcn_update_dpp(0, __float_as_int(v), 0x140, 0xF, 0xF, true); v += __int_as_float(x); // row_mirror
    x = __builtin_amdgcn_update_dpp(0, __float_as_int(v), 0x142, 0xF, 0xF, true); v += __int_as_float(x); // row_bcast15
    x = __builtin_amdgcn_update_dpp(0, __float_as_int(v), 0x143, 0xF, 0xF, true); v += __int_as_float(x); // row_bcast31
    return v;
}

// ---- pass 2: det-major waves. One wave finishes PXW pixels. ----
__global__ __launch_bounds__(256, 4)
void bp_det(const uint4* __restrict__ ws,
            const float* __restrict__ lut,
            float* __restrict__ out) {
    const int tid  = threadIdx.x;
    const int lane = tid & 63;
    const int wid  = (blockIdx.x << 2) + (tid >> 6);   // global wave id
    const int px0  = wid * PXW;

    const int d0 = 2 * lane, d1 = 2 * lane + 1;
    const float C = 6.28318530717958647692f / 127.0f;
    const float apod0 = 0.5f - 0.5f * __cosf((float)d0 * C);
    const float apod1 = 0.5f - 0.5f * __cosf((float)d1 * C);

    const uint4* row0 = ws + (size_t)d0 * NT;
    const uint4* row1 = ws + (size_t)d1 * NT;
    const uv4*  lutp  = (const uv4*)lut + (size_t)px0 * 64 + lane;

    // ---- phase A: all lut loads in flight (coalesced 1KB/wave each) ----
    uv4 l[PXW];
#pragma unroll
    for (int j = 0; j < PXW; ++j)
        l[j] = __builtin_nontemporal_load(lutp + (size_t)j * 64);

    float acc[PXW][NB];
#pragma unroll
    for (int j = 0; j < PXW; ++j)
#pragma unroll
        for (int b = 0; b < NB; ++b) acc[j][b] = 0.0f;

    // ---- phase B: two 4-px subgroups; gathers issued before any use ----
#pragma unroll
    for (int g = 0; g < PXW / 4; ++g) {
        uint4 g0[4], g1[4];
        unsigned a20[4], a21[4];
        float w0[4], w1[4];
#pragma unroll
        for (int jj = 0; jj < 4; ++jj) {
            const uv4 lv = l[g * 4 + jj];
            int   k0  = (int)__uint_as_float(lv.x);
            bool  v0  = (unsigned)k0 < (unsigned)(NT - 1);
            int   k1  = (int)__uint_as_float(lv.z);
            bool  v1  = (unsigned)k1 < (unsigned)(NT - 1);
            w0[jj] = v0 ? apod0 : 0.0f;
            w1[jj] = v1 ? apod1 : 0.0f;
            __half2 h;
            h = __float2half2_rn(__uint_as_float(lv.y)); a20[jj] = *(unsigned*)&h;
            h = __float2half2_rn(__uint_as_float(lv.w)); a21[jj] = *(unsigned*)&h;
            g0[jj] = row0[v0 ? k0 : 0];     // 16B: S[k],S[k+1] x 4 batches
            g1[jj] = row1[v1 ? k1 : 0];
        }
#pragma unroll
        for (int jj = 0; jj < 4; ++jj) {
            const int j = g * 4 + jj;
            {
                uint4 e = g0[jj];
                __half2 a01 = *(__half2*)&e.x, a23 = *(__half2*)&e.y;
                __half2 b01 = *(__half2*)&e.z, b23 = *(__half2*)&e.w;
                __half2 a2  = *(__half2*)&a20[jj];
                __half2 s01 = __hfma2(a2, __hsub2(b01, a01), a01);
                __half2 s23 = __hfma2(a2, __hsub2(b23, a23), a23);
                float2 f01 = __half22float2(s01);
                float2 f23 = __half22float2(s23);
                acc[j][0] = fmaf(w0[jj], f01.x, acc[j][0]);
                acc[j][1] = fmaf(w0[jj], f01.y, acc[j][1]);
                acc[j][2] = fmaf(w0[jj], f23.x, acc[j][2]);
                acc[j][3] = fmaf(w0[jj], f23.y, acc[j][3]);
            }
            {
                uint4 e = g1[jj];
                __half2 a01 = *(__half2*)&e.x, a23 = *(__half2*)&e.y;
                __half2 b01 = *(__half2*)&e.z, b23 = *(__half2*)&e.w;
                __half2 a2  = *(__half2*)&a21[jj];
                __half2 s01 = __hfma2(a2, __hsub2(b01, a01), a01);
                __half2 s23 = __hfma2(a2, __hsub2(b23, a23), a23);
                float2 f01 = __half22float2(s01);
                float2 f23 = __half22float2(s23);
                acc[j][0] = fmaf(w1[jj], f01.x, acc[j][0]);
                acc[j][1] = fmaf(w1[jj], f01.y, acc[j][1]);
                acc[j][2] = fmaf(w1[jj], f23.x, acc[j][2]);
                acc[j][3] = fmaf(w1[jj], f23.y, acc[j][3]);
            }
        }
    }

    // ---- phase C: reduce + commit (no loads pending) ----
    float res[NB] = {0.f, 0.f, 0.f, 0.f};
#pragma unroll
    for (int j = 0; j < PXW; ++j) {
#pragma unroll
        for (int b = 0; b < NB; ++b) {
            float t = wave_reduce_add(acc[j][b]);
            float t63 = __shfl(t, 63, 64);             // uniform idx -> v_readlane
            res[b] = (lane == j) ? t63 : res[b];       // v_cndmask commit
        }
    }

    const float inv_norm = 1.0f / 63.5f;               // sum(apod) == 63.5 exactly
    if (lane < PXW) {
#pragma unroll
        for (int b = 0; b < NB; ++b)
            out[(size_t)b * NPIX + px0 + lane] = res[b] * inv_norm;
    }
}

// ================= legacy R11 path (ws in [2MB,4MB)) =================
#define DBLOCK  8
#define DQ      4
#define PTILE   2048
#define THREADS 1024
#define PXPT    (PTILE / THREADS)

__global__ __launch_bounds__(256)
void cvt_kernel(const float* __restrict__ sino, uint2* __restrict__ ws16) {
    const int id = blockIdx.x * 256 + threadIdx.x;
    float v0 = sino[id];
    float v1 = sino[id + NDET * NT];
    float v2 = sino[id + 2 * NDET * NT];
    float v3 = sino[id + 3 * NDET * NT];
    __half2 h01 = __floats2half2_rn(v0, v1);
    __half2 h23 = __floats2half2_rn(v2, v3);
    uint2 u;
    u.x = *(const unsigned*)&h01;
    u.y = *(const unsigned*)&h23;
    ws16[id] = u;
}

__global__ __launch_bounds__(THREADS, 4)
void bp_kernel(const uint2* __restrict__ ws16,
               const float* __restrict__ lut,
               float* __restrict__ out) {
    __shared__ uint2 lds2[DQ * NT];

    const int tid   = threadIdx.x;
    const int octet = blockIdx.x & 15;
    const int tile  = blockIdx.x >> 4;
    const int d0    = octet * DBLOCK;
    const int px0   = tile * PTILE;

    float apod[DBLOCK];
#pragma unroll
    for (int j = 0; j < DBLOCK; ++j) {
        float x = (float)(d0 + j) * (6.28318530717958647692f / 127.0f);
        apod[j] = 0.5f - 0.5f * __cosf(x);
    }

    float acc[PXPT][NB];
#pragma unroll
    for (int i = 0; i < PXPT; ++i)
#pragma unroll
        for (int b = 0; b < NB; ++b) acc[i][b] = 0.0f;

    const float4* lp[PXPT];
#pragma unroll
    for (int i = 0; i < PXPT; ++i)
        lp[i] = (const float4*)
            (lut + ((size_t)(px0 + tid + i * THREADS) * NDET + d0) * 2);

    float4 Lcur[PXPT][2];
#pragma unroll
    for (int i = 0; i < PXPT; ++i) {
        Lcur[i][0] = lp[i][0];
        Lcur[i][1] = lp[i][1];
    }

    {
        const uint4* src = (const uint4*)(ws16 + (size_t)d0 * NT);
        uint4* dst = (uint4*)lds2;
#pragma unroll
        for (int r = 0; r < 4; ++r) dst[tid + r * THREADS] = src[tid + r * THREADS];
    }
    __syncthreads();

    float4 Lnext[PXPT][2];
#pragma unroll
    for (int i = 0; i < PXPT; ++i) {
        Lnext[i][0] = lp[i][2];
        Lnext[i][1] = lp[i][3];
    }

    auto gather = [&](const float4 (*Lq)[2], int jbase) {
#pragma unroll
        for (int i = 0; i < PXPT; ++i) {
#pragma unroll
            for (int q = 0; q < 2; ++q) {
                float4 Le = Lq[i][q];
#pragma unroll
                for (int h = 0; h < 2; ++h) {
                    float kf = h ? Le.z : Le.x;
                    float af = h ? Le.w : Le.y;
                    int   dl = q * 2 + h;
                    int k = (int)kf;
                    bool valid = (unsigned)k < (unsigned)(NT - 1);
                    float w  = valid ? apod[jbase + dl] : 0.0f;
                    int  k0  = valid ? k : 0;
                    uint2 e0 = lds2[dl * NT + k0];
                    uint2 e1 = lds2[dl * NT + k0 + 1];
                    __half2 a01 = *(__half2*)&e0.x, a23 = *(__half2*)&e0.y;
                    __half2 b01 = *(__half2*)&e1.x, b23 = *(__half2*)&e1.y;
                    __half2 a2  = __float2half2_rn(af);
                    __half2 s01 = __hfma2(a2, __hsub2(b01, a01), a01);
                    __half2 s23 = __hfma2(a2, __hsub2(b23, a23), a23);
                    float2 f01 = __half22float2(s01);
                    float2 f23 = __half22float2(s23);
                    acc[i][0] = fmaf(w, f01.x, acc[i][0]);
                    acc[i][1] = fmaf(w, f01.y, acc[i][1]);
                    acc[i][2] = fmaf(w, f23.x, acc[i][2]);
                    acc[i][3] = fmaf(w, f23.y, acc[i][3]);
                }
            }
        }
    };

    gather(Lcur, 0);
    __syncthreads();

    {
        const uint4* src = (const uint4*)(ws16 + (size_t)(d0 + DQ) * NT);
        uint4* dst = (uint4*)lds2;
#pragma unroll
        for (int r = 0; r < 4; ++r) dst[tid + r * THREADS] = src[tid + r * THREADS];
    }
    __syncthreads();

    gather(Lnext, DQ);

    const float inv_norm = 1.0f / 63.5f;
#pragma unroll
    for (int i = 0; i < PXPT; ++i) {
        const int px = px0 + tid + i * THREADS;
#pragma unroll
        for (int b = 0; b < NB; ++b) {
            atomicAdd(&out[(size_t)b * NPIX + px], acc[i][b] * inv_norm);
        }
    }
}

// ---- fallback (ws too small): fp32 staging + cvt in-kernel ----
__global__ __launch_bounds__(512, 4)
void bp_fallback(const float* __restrict__ sino,
                 const float* __restrict__ lut,
                 float* __restrict__ out) {
    __shared__ __half2 lds[4][NT];
    const int tid   = threadIdx.x;
    const int octet = blockIdx.x & 15;
    const int tile  = blockIdx.x >> 4;
    const int d0    = octet * DBLOCK;
    const int px0   = tile * 1024;
    float apod[DBLOCK];
#pragma unroll
    for (int j = 0; j < DBLOCK; ++j) {
        float x = (float)(d0 + j) * (6.28318530717958647692f / 127.0f);
        apod[j] = 0.5f - 0.5f * __cosf(x);
    }
    float4 L[2][4];
#pragma unroll
    for (int i = 0; i < 2; ++i) {
        const float4* lq = (const float4*)
            (lut + ((size_t)(px0 + tid + i * 512) * NDET + d0) * 2);
#pragma unroll
        for (int q = 0; q < 4; ++q) L[i][q] = lq[q];
    }
    float acc[2][NB];
#pragma unroll
    for (int i = 0; i < 2; ++i)
#pragma unroll
        for (int b = 0; b < NB; ++b) acc[i][b] = 0.0f;
    const float4* s4 = (const float4*)sino;
    for (int ph = 0; ph < 4; ++ph) {
        const int b0  = (ph >> 1) * 2;
        const int dh  = ph & 1;
        const int dg0 = d0 + dh * 4;
        if (ph) __syncthreads();
        for (int f = tid; f < 4 * (NT / 4); f += 512) {
            int dl = f >> 9;
            int t4 = f & 511;
            size_t row = ((size_t)b0 * NDET + dg0 + dl) * (NT / 4) + t4;
            float4 ve = s4[row];
            float4 vo = s4[row + (size_t)NDET * (NT / 4)];
            __half2* dstp = &lds[dl][t4 * 4];
            dstp[0] = __floats2half2_rn(ve.x, vo.x);
            dstp[1] = __floats2half2_rn(ve.y, vo.y);
            dstp[2] = __floats2half2_rn(ve.z, vo.z);
            dstp[3] = __floats2half2_rn(ve.w, vo.w);
        }
        __syncthreads();
#pragma unroll
        for (int i = 0; i < 2; ++i) {
#pragma unroll
            for (int q2 = 0; q2 < 2; ++q2) {
                float4 Lq = L[i][dh * 2 + q2];
#pragma unroll
                for (int h = 0; h < 2; ++h) {
                    float kf = h ? Lq.z : Lq.x;
                    float af = h ? Lq.w : Lq.y;
                    int   dl = q2 * 2 + h;
                    int k = (int)kf;
                    bool valid = (unsigned)k < (unsigned)(NT - 1);
                    float w  = valid ? apod[dh * 4 + dl] : 0.0f;
                    int  k0  = valid ? k : 0;
                    __half2 s0v = lds[dl][k0];
                    __half2 s1v = lds[dl][k0 + 1];
                    __half2 a2  = __float2half2_rn(af);
                    __half2 sk  = __hfma2(a2, __hsub2(s1v, s0v), s0v);
                    float2  fv  = __half22float2(sk);
                    acc[i][b0 + 0] = fmaf(w, fv.x, acc[i][b0 + 0]);
                    acc[i][b0 + 1] = fmaf(w, fv.y, acc[i][b0 + 1]);
                }
            }
        }
    }
    const float inv_norm = 1.0f / 63.5f;
#pragma unroll
    for (int i = 0; i < 2; ++i) {
        const int px = px0 + tid + i * 512;
#pragma unroll
        for (int b = 0; b < NB; ++b)
            atomicAdd(&out[(size_t)b * NPIX + px], acc[i][b] * inv_norm);
    }
}

extern "C" void kernel_launch(void* const* d_in, const int* in_sizes, int n_in,
                              void* d_out, int out_size, void* d_ws, size_t ws_size,
                              hipStream_t stream) {
    const float* sino = (const float*)d_in[0];
    const float* lut  = (const float*)d_in[1];
    float* out = (float*)d_out;

    const size_t ws_new = (size_t)NDET * NT * sizeof(uint4);   // 4 MB
    const size_t ws_old = (size_t)NDET * NT * sizeof(uint2);   // 2 MB

    if (ws_size >= ws_new) {
        uint4* ws = (uint4*)d_ws;
        cvt16b<<<dim3(NDET * NT / 256), dim3(256), 0, stream>>>(sino, ws);
        // 65536 px / 8 per wave = 8192 waves = 2048 blocks x 4 waves.
        // No memset: every output written exactly once (plain stores).
        bp_det<<<dim3(NPIX / PXW / 4), dim3(256), 0, stream>>>(ws, lut, out);
    } else if (ws_size >= ws_old) {
        (void)hipMemsetAsync(d_out, 0, (size_t)out_size * sizeof(float), stream);
        uint2* ws16 = (uint2*)d_ws;
        cvt_kernel<<<dim3(NDET * NT / 256), dim3(256), 0, stream>>>(sino, ws16);
        bp_kernel<<<dim3(512), dim3(THREADS), 0, stream>>>(ws16, lut, out);
    } else {
        (void)hipMemsetAsync(d_out, 0, (size_t)out_size * sizeof(float), stream);
        bp_fallback<<<dim3(1024), dim3(512), 0, stream>>>(sino, lut, out);
    }
}

// Round 4
// 134.985 us; speedup vs baseline: 1.0724x; 1.0724x over previous
//
#include <hip/hip_runtime.h>
#include <hip/hip_fp16.h>

// BackProjectionLinear: out[b,p] = sum_d apod[d] * lerp(sino[b,d], k[p,d], a[p,d]) / 63.5
// B=4, N_DET=128, N_T=2048, pixels=65536.
//
// R14: force the pipeline the compiler refuses to keep. R12/R13 post-mortem:
// VGPR=36 both rounds -> LLVM sinks loads to uses, destroying MLP; both
// latency-bound at 57us despite all throughput floors being <15us. Fix with
// compiler-proof mechanisms:
//  - lut stream via global_load_lds DMA into a wave-PRIVATE 4x1KB LDS ring
//    (no barriers, no VGPR round-trip, nothing for regalloc to sink).
//  - counted s_waitcnt vmcnt(N) asm fences (memory clobber) between pixel
//    iterations: loads/DMA cannot cross them. Steady queue at iter p top =
//    [D(p+2), G(p)a, G(p)b, D(p+3)] -> vmcnt(1) completes pixel-p gathers
//    while 2 DMAs stay in flight => continuous HBM stream.
//  - per iter: lerp(p) | ds_read lut(p+1) | issue 2 L2 gathers | DMA(p+4).
//  - det-major lanes (lane=det pair): lut DMA is perfectly coalesced
//    (1KB/wave/pixel, 16 lines); gathers hit L2-resident 4MB ws16b.
//  - acc[16px][4b] per lane; all DPP reduces deferred to wave end.
// Canary: VGPR 90-128 (pipeline survived), WRITE_SIZE ~1.2MB (no spill).

#define NB      4
#define NDET    128
#define NT      2048
#define NPIX    65536
#define NPXW    16                   // pixels per wave
#define DEPTH   4                    // lut LDS ring depth (1KB each)

typedef __attribute__((address_space(3))) void lds_void;
typedef const __attribute__((address_space(1))) void gbl_void;

// ---- pass 1: sino fp32[4][128][2048] -> ws16b[det][t] = uint4
//      {h2(b01@t), h2(b23@t), h2(b01@t+1), h2(b23@t+1)}  (4 MB) ----
__global__ __launch_bounds__(256)
void cvt16b(const float* __restrict__ sino, uint4* __restrict__ ws) {
    const int id = blockIdx.x * 256 + threadIdx.x;     // det*NT + t
    const int t  = id & (NT - 1);
    float c0 = sino[id];
    float c1 = sino[id +     NDET * NT];
    float c2 = sino[id + 2 * NDET * NT];
    float c3 = sino[id + 3 * NDET * NT];
    const int idn = (t < NT - 1) ? id + 1 : id;        // t=2047 never gathered
    float n0 = sino[idn];
    float n1 = sino[idn +     NDET * NT];
    float n2 = sino[idn + 2 * NDET * NT];
    float n3 = sino[idn + 3 * NDET * NT];
    uint4 u;
    __half2 h;
    h = __floats2half2_rn(c0, c1); u.x = *(unsigned*)&h;
    h = __floats2half2_rn(c2, c3); u.y = *(unsigned*)&h;
    h = __floats2half2_rn(n0, n1); u.z = *(unsigned*)&h;
    h = __floats2half2_rn(n2, n3); u.w = *(unsigned*)&h;
    ws[id] = u;
}

// 64-lane f32 add-reduce on the VALU pipe. Result valid in lane 63.
__device__ __forceinline__ float wave_reduce_add(float v) {
    int x;
    x = __builtin_amdgcn_update_dpp(0, __float_as_int(v), 0xB1,  0xF, 0xF, true); v += __int_as_float(x); // quad_perm [1,0,3,2]
    x = __builtin_amdgcn_update_dpp(0, __float_as_int(v), 0x4E,  0xF, 0xF, true); v += __int_as_float(x); // quad_perm [2,3,0,1]
    x = __builtin_amdgcn_update_dpp(0, __float_as_int(v), 0x141, 0xF, 0xF, true); v += __int_as_float(x); // row_half_mirror
    x = __builtin_amdgcn_update_dpp(0, __float_as_int(v), 0x140, 0xF, 0xF, true); v += __int_as_float(x); // row_mirror
    x = __builtin_amdgcn_update_dpp(0, __float_as_int(v), 0x142, 0xF, 0xF, true); v += __int_as_float(x); // row_bcast15
    x = __builtin_amdgcn_update_dpp(0, __float_as_int(v), 0x143, 0xF, 0xF, true); v += __int_as_float(x); // row_bcast31
    return v;
}

// ---- pass 2: det-major waves, DMA-pipelined lut, L2 gathers ----
__global__ __launch_bounds__(256, 4)
void bp_det(const uint4* __restrict__ ws,
            const float* __restrict__ lut,
            float* __restrict__ out) {
    __shared__ uint4 lbuf[4][DEPTH][64];               // [wave][ring][lane] 16KB

    const int tid  = threadIdx.x;
    const int lane = tid & 63;
    const int wv   = tid >> 6;
    const int wid  = (blockIdx.x << 2) + wv;           // global wave id
    const int px0  = wid * NPXW;

    const int da = 2 * lane, db = 2 * lane + 1;
    const float C = 6.28318530717958647692f / 127.0f;
    const float apodA = 0.5f - 0.5f * __cosf((float)da * C);
    const float apodB = 0.5f - 0.5f * __cosf((float)db * C);

    const uint4* rowA = ws + (size_t)da * NT;
    const uint4* rowB = ws + (size_t)db * NT;

    // per-lane global src: pixel p's 16B for dets (da,db); wave covers 1KB.
    const float* lsrc = lut + (size_t)px0 * (NDET * 2) + lane * 4;

    auto DMA = [&](int p) {
        __builtin_amdgcn_global_load_lds(
            (gbl_void*)(lsrc + (size_t)p * (NDET * 2)),
            (lds_void*)&lbuf[wv][p & (DEPTH - 1)][0],
            16, 0, 0);                                 // lds dst = base + lane*16
    };

    float acc[NPXW][NB];
#pragma unroll
    for (int p = 0; p < NPXW; ++p)
#pragma unroll
        for (int b = 0; b < NB; ++b) acc[p][b] = 0.0f;

    // pipeline registers: gathered taps + weights for the "current" pixel
    uint4 cA, cB;
    float cwA, cwB;
    unsigned caA, caB;

    auto DECODE = [&](uint4 e) {                       // read lut entry, issue gathers
        int k0 = (int)__uint_as_float(e.x);
        int k1 = (int)__uint_as_float(e.z);
        bool v0 = (unsigned)k0 < (unsigned)(NT - 1);
        bool v1 = (unsigned)k1 < (unsigned)(NT - 1);
        cwA = v0 ? apodA : 0.0f;
        cwB = v1 ? apodB : 0.0f;
        __half2 h;
        h = __float2half2_rn(__uint_as_float(e.y)); caA = *(unsigned*)&h;
        h = __float2half2_rn(__uint_as_float(e.w)); caB = *(unsigned*)&h;
        cA = rowA[v0 ? k0 : 0];                        // 16B: S[k],S[k+1] x 4 batches
        cB = rowB[v1 ? k1 : 0];
    };

    auto LERP = [&](float (&a4)[NB]) {
        {
            uint4 e = cA;
            __half2 a01 = *(__half2*)&e.x, a23 = *(__half2*)&e.y;
            __half2 b01 = *(__half2*)&e.z, b23 = *(__half2*)&e.w;
            __half2 a2  = *(__half2*)&caA;
            __half2 s01 = __hfma2(a2, __hsub2(b01, a01), a01);
            __half2 s23 = __hfma2(a2, __hsub2(b23, a23), a23);
            float2 f01 = __half22float2(s01), f23 = __half22float2(s23);
            a4[0] = fmaf(cwA, f01.x, a4[0]);
            a4[1] = fmaf(cwA, f01.y, a4[1]);
            a4[2] = fmaf(cwA, f23.x, a4[2]);
            a4[3] = fmaf(cwA, f23.y, a4[3]);
        }
        {
            uint4 e = cB;
            __half2 a01 = *(__half2*)&e.x, a23 = *(__half2*)&e.y;
            __half2 b01 = *(__half2*)&e.z, b23 = *(__half2*)&e.w;
            __half2 a2  = *(__half2*)&caB;
            __half2 s01 = __hfma2(a2, __hsub2(b01, a01), a01);
            __half2 s23 = __hfma2(a2, __hsub2(b23, a23), a23);
            float2 f01 = __half22float2(s01), f23 = __half22float2(s23);
            a4[0] = fmaf(cwB, f01.x, a4[0]);
            a4[1] = fmaf(cwB, f01.y, a4[1]);
            a4[2] = fmaf(cwB, f23.x, a4[2]);
            a4[3] = fmaf(cwB, f23.y, a4[3]);
        }
    };

    // ---- prologue: fill ring, decode pixel 0 ----
    DMA(0); DMA(1); DMA(2);
    asm volatile("s_waitcnt vmcnt(2)" ::: "memory");   // D0 done
    __builtin_amdgcn_sched_barrier(0);
    DECODE(lbuf[wv][0][lane]);                          // issues G0a,G0b
    DMA(3);                                             // queue: D1 D2 G0ab D3

    // ---- main loop: fences pin each iteration's memory ops ----
#pragma unroll
    for (int p = 0; p < NPXW; ++p) {
        if (p + 4 < NPXW) {
            // steady queue: [D(p+2), G(p)a, G(p)b, D(p+3)] -> complete G(p),
            // keep newest DMA in flight.
            asm volatile("s_waitcnt vmcnt(1)" ::: "memory");
        } else {
            // tail: DMAs exhausted; drain to guarantee G(p) complete.
            asm volatile("s_waitcnt vmcnt(0)" ::: "memory");
        }
        __builtin_amdgcn_sched_barrier(0);
        LERP(acc[p]);                                  // pixel p (gathered last iter)
        if (p + 1 < NPXW) DECODE(lbuf[wv][(p + 1) & (DEPTH - 1)][lane]);
        if (p + 4 < NPXW) DMA(p + 4);
    }

    // ---- reduce + commit (no loads pending) ----
    float res[NB] = {0.f, 0.f, 0.f, 0.f};
#pragma unroll
    for (int j = 0; j < NPXW; ++j) {
#pragma unroll
        for (int b = 0; b < NB; ++b) {
            float t = wave_reduce_add(acc[j][b]);
            float t63 = __shfl(t, 63, 64);             // uniform idx -> v_readlane
            res[b] = (lane == j) ? t63 : res[b];       // v_cndmask commit
        }
    }

    const float inv_norm = 1.0f / 63.5f;               // sum(apod) == 63.5 exactly
    if (lane < NPXW) {
#pragma unroll
        for (int b = 0; b < NB; ++b)
            out[(size_t)b * NPIX + px0 + lane] = res[b] * inv_norm;
    }
}

// ================= legacy R11 path (ws in [2MB,4MB)) =================
#define DBLOCK  8
#define DQ      4
#define PTILE   2048
#define THREADS 1024
#define PXPT    (PTILE / THREADS)

__global__ __launch_bounds__(256)
void cvt_kernel(const float* __restrict__ sino, uint2* __restrict__ ws16) {
    const int id = blockIdx.x * 256 + threadIdx.x;
    float v0 = sino[id];
    float v1 = sino[id + NDET * NT];
    float v2 = sino[id + 2 * NDET * NT];
    float v3 = sino[id + 3 * NDET * NT];
    __half2 h01 = __floats2half2_rn(v0, v1);
    __half2 h23 = __floats2half2_rn(v2, v3);
    uint2 u;
    u.x = *(const unsigned*)&h01;
    u.y = *(const unsigned*)&h23;
    ws16[id] = u;
}

__global__ __launch_bounds__(THREADS, 4)
void bp_kernel(const uint2* __restrict__ ws16,
               const float* __restrict__ lut,
               float* __restrict__ out) {
    __shared__ uint2 lds2[DQ * NT];

    const int tid   = threadIdx.x;
    const int octet = blockIdx.x & 15;
    const int tile  = blockIdx.x >> 4;
    const int d0    = octet * DBLOCK;
    const int px0   = tile * PTILE;

    float apod[DBLOCK];
#pragma unroll
    for (int j = 0; j < DBLOCK; ++j) {
        float x = (float)(d0 + j) * (6.28318530717958647692f / 127.0f);
        apod[j] = 0.5f - 0.5f * __cosf(x);
    }

    float acc[PXPT][NB];
#pragma unroll
    for (int i = 0; i < PXPT; ++i)
#pragma unroll
        for (int b = 0; b < NB; ++b) acc[i][b] = 0.0f;

    const float4* lp[PXPT];
#pragma unroll
    for (int i = 0; i < PXPT; ++i)
        lp[i] = (const float4*)
            (lut + ((size_t)(px0 + tid + i * THREADS) * NDET + d0) * 2);

    float4 Lcur[PXPT][2];
#pragma unroll
    for (int i = 0; i < PXPT; ++i) {
        Lcur[i][0] = lp[i][0];
        Lcur[i][1] = lp[i][1];
    }

    {
        const uint4* src = (const uint4*)(ws16 + (size_t)d0 * NT);
        uint4* dst = (uint4*)lds2;
#pragma unroll
        for (int r = 0; r < 4; ++r) dst[tid + r * THREADS] = src[tid + r * THREADS];
    }
    __syncthreads();

    float4 Lnext[PXPT][2];
#pragma unroll
    for (int i = 0; i < PXPT; ++i) {
        Lnext[i][0] = lp[i][2];
        Lnext[i][1] = lp[i][3];
    }

    auto gather = [&](const float4 (*Lq)[2], int jbase) {
#pragma unroll
        for (int i = 0; i < PXPT; ++i) {
#pragma unroll
            for (int q = 0; q < 2; ++q) {
                float4 Le = Lq[i][q];
#pragma unroll
                for (int h = 0; h < 2; ++h) {
                    float kf = h ? Le.z : Le.x;
                    float af = h ? Le.w : Le.y;
                    int   dl = q * 2 + h;
                    int k = (int)kf;
                    bool valid = (unsigned)k < (unsigned)(NT - 1);
                    float w  = valid ? apod[jbase + dl] : 0.0f;
                    int  k0  = valid ? k : 0;
                    uint2 e0 = lds2[dl * NT + k0];
                    uint2 e1 = lds2[dl * NT + k0 + 1];
                    __half2 a01 = *(__half2*)&e0.x, a23 = *(__half2*)&e0.y;
                    __half2 b01 = *(__half2*)&e1.x, b23 = *(__half2*)&e1.y;
                    __half2 a2  = __float2half2_rn(af);
                    __half2 s01 = __hfma2(a2, __hsub2(b01, a01), a01);
                    __half2 s23 = __hfma2(a2, __hsub2(b23, a23), a23);
                    float2 f01 = __half22float2(s01);
                    float2 f23 = __half22float2(s23);
                    acc[i][0] = fmaf(w, f01.x, acc[i][0]);
                    acc[i][1] = fmaf(w, f01.y, acc[i][1]);
                    acc[i][2] = fmaf(w, f23.x, acc[i][2]);
                    acc[i][3] = fmaf(w, f23.y, acc[i][3]);
                }
            }
        }
    };

    gather(Lcur, 0);
    __syncthreads();

    {
        const uint4* src = (const uint4*)(ws16 + (size_t)(d0 + DQ) * NT);
        uint4* dst = (uint4*)lds2;
#pragma unroll
        for (int r = 0; r < 4; ++r) dst[tid + r * THREADS] = src[tid + r * THREADS];
    }
    __syncthreads();

    gather(Lnext, DQ);

    const float inv_norm = 1.0f / 63.5f;
#pragma unroll
    for (int i = 0; i < PXPT; ++i) {
        const int px = px0 + tid + i * THREADS;
#pragma unroll
        for (int b = 0; b < NB; ++b) {
            atomicAdd(&out[(size_t)b * NPIX + px], acc[i][b] * inv_norm);
        }
    }
}

// ---- fallback (ws too small): fp32 staging + cvt in-kernel ----
__global__ __launch_bounds__(512, 4)
void bp_fallback(const float* __restrict__ sino,
                 const float* __restrict__ lut,
                 float* __restrict__ out) {
    __shared__ __half2 lds[4][NT];
    const int tid   = threadIdx.x;
    const int octet = blockIdx.x & 15;
    const int tile  = blockIdx.x >> 4;
    const int d0    = octet * DBLOCK;
    const int px0   = tile * 1024;
    float apod[DBLOCK];
#pragma unroll
    for (int j = 0; j < DBLOCK; ++j) {
        float x = (float)(d0 + j) * (6.28318530717958647692f / 127.0f);
        apod[j] = 0.5f - 0.5f * __cosf(x);
    }
    float4 L[2][4];
#pragma unroll
    for (int i = 0; i < 2; ++i) {
        const float4* lq = (const float4*)
            (lut + ((size_t)(px0 + tid + i * 512) * NDET + d0) * 2);
#pragma unroll
        for (int q = 0; q < 4; ++q) L[i][q] = lq[q];
    }
    float acc[2][NB];
#pragma unroll
    for (int i = 0; i < 2; ++i)
#pragma unroll
        for (int b = 0; b < NB; ++b) acc[i][b] = 0.0f;
    const float4* s4 = (const float4*)sino;
    for (int ph = 0; ph < 4; ++ph) {
        const int b0  = (ph >> 1) * 2;
        const int dh  = ph & 1;
        const int dg0 = d0 + dh * 4;
        if (ph) __syncthreads();
        for (int f = tid; f < 4 * (NT / 4); f += 512) {
            int dl = f >> 9;
            int t4 = f & 511;
            size_t row = ((size_t)b0 * NDET + dg0 + dl) * (NT / 4) + t4;
            float4 ve = s4[row];
            float4 vo = s4[row + (size_t)NDET * (NT / 4)];
            __half2* dstp = &lds[dl][t4 * 4];
            dstp[0] = __floats2half2_rn(ve.x, vo.x);
            dstp[1] = __floats2half2_rn(ve.y, vo.y);
            dstp[2] = __floats2half2_rn(ve.z, vo.z);
            dstp[3] = __floats2half2_rn(ve.w, vo.w);
        }
        __syncthreads();
#pragma unroll
        for (int i = 0; i < 2; ++i) {
#pragma unroll
            for (int q2 = 0; q2 < 2; ++q2) {
                float4 Lq = L[i][dh * 2 + q2];
#pragma unroll
                for (int h = 0; h < 2; ++h) {
                    float kf = h ? Lq.z : Lq.x;
                    float af = h ? Lq.w : Lq.y;
                    int   dl = q2 * 2 + h;
                    int k = (int)kf;
                    bool valid = (unsigned)k < (unsigned)(NT - 1);
                    float w  = valid ? apod[dh * 4 + dl] : 0.0f;
                    int  k0  = valid ? k : 0;
                    __half2 s0v = lds[dl][k0];
                    __half2 s1v = lds[dl][k0 + 1];
                    __half2 a2  = __float2half2_rn(af);
                    __half2 sk  = __hfma2(a2, __hsub2(s1v, s0v), s0v);
                    float2  fv  = __half22float2(sk);
                    acc[i][b0 + 0] = fmaf(w, fv.x, acc[i][b0 + 0]);
                    acc[i][b0 + 1] = fmaf(w, fv.y, acc[i][b0 + 1]);
                }
            }
        }
    }
    const float inv_norm = 1.0f / 63.5f;
#pragma unroll
    for (int i = 0; i < 2; ++i) {
        const int px = px0 + tid + i * 512;
#pragma unroll
        for (int b = 0; b < NB; ++b)
            atomicAdd(&out[(size_t)b * NPIX + px], acc[i][b] * inv_norm);
    }
}

extern "C" void kernel_launch(void* const* d_in, const int* in_sizes, int n_in,
                              void* d_out, int out_size, void* d_ws, size_t ws_size,
                              hipStream_t stream) {
    const float* sino = (const float*)d_in[0];
    const float* lut  = (const float*)d_in[1];
    float* out = (float*)d_out;

    const size_t ws_new = (size_t)NDET * NT * sizeof(uint4);   // 4 MB
    const size_t ws_old = (size_t)NDET * NT * sizeof(uint2);   // 2 MB

    if (ws_size >= ws_new) {
        uint4* ws = (uint4*)d_ws;
        cvt16b<<<dim3(NDET * NT / 256), dim3(256), 0, stream>>>(sino, ws);
        // 65536 px / 16 per wave = 4096 waves = 1024 blocks x 4 waves
        // (4 blocks/CU, one generation). No memset: plain stores, each
        // output written exactly once.
        bp_det<<<dim3(NPIX / NPXW / 4), dim3(256), 0, stream>>>(ws, lut, out);
    } else if (ws_size >= ws_old) {
        (void)hipMemsetAsync(d_out, 0, (size_t)out_size * sizeof(float), stream);
        uint2* ws16 = (uint2*)d_ws;
        cvt_kernel<<<dim3(NDET * NT / 256), dim3(256), 0, stream>>>(sino, ws16);
        bp_kernel<<<dim3(512), dim3(THREADS), 0, stream>>>(ws16, lut, out);
    } else {
        (void)hipMemsetAsync(d_out, 0, (size_t)out_size * sizeof(float), stream);
        bp_fallback<<<dim3(1024), dim3(512), 0, stream>>>(sino, lut, out);
    }
}